// Round 10
// baseline (217.112 us; speedup 1.0000x reference)
//
#include <hip/hip_runtime.h>

#define D 128
#define SCAN_B 1024

static inline int ceil_div_ll(long long a, int b) { return (int)((a + b - 1) / b); }

typedef unsigned int uint32;
typedef __attribute__((ext_vector_type(8))) short short8;   // 8 x bf16 (4 VGPRs)
typedef __attribute__((ext_vector_type(4))) float f32x4;    // MFMA C/D

__device__ __forceinline__ float blo(uint32 u) { return __uint_as_float(u << 16); }
__device__ __forceinline__ float bhi(uint32 u) { return __uint_as_float(u & 0xffff0000u); }
__device__ __forceinline__ uint32 bpack(float a, float b) {   // 2x f32 -> bf16x2 RTNE
    uint32 ua = __float_as_uint(a), ub = __float_as_uint(b);
    ua += 0x7fffu + ((ua >> 16) & 1u);
    ub += 0x7fffu + ((ub >> 16) & 1u);
    return (ua >> 16) | (ub & 0xffff0000u);
}

// zero packed histogram
__global__ void k_init(uint32* __restrict__ cnt, int n) {
    int i = blockIdx.x * blockDim.x + threadIdx.x;
    if (i < n) cnt[i] = 0;
}

// FUSED: [0,ncount): packed degree histogram (atomic-bound)
//        [ncount,ncount+ncvt): x f32 -> bf16 (BW-bound, hides under atomics)
//        [ncount+ncvt, +8): W -> MFMA B-fragment repack
__global__ __launch_bounds__(256) void k_fused(
        const int2* __restrict__ rows2, const int2* __restrict__ cols2,
        uint32* __restrict__ cnt, int E2, int odd,
        const int* __restrict__ rows, const int* __restrict__ cols,
        const float4* __restrict__ x, uint4* __restrict__ xh, long long totcvt,
        const float* __restrict__ Wm, uint4* __restrict__ wfrag,
        int ncount, int ncvt) {
    const int b = blockIdx.x;
    if (b < ncount) {
        // ---- packed histogram: cnt[c] += 1 (low 16), cnt[r] += 1<<16 ----
        const int t = b * 256 + threadIdx.x;
        if (t < E2) {
            const int2 r2 = rows2[t];
            const int2 c2 = cols2[t];
            atomicAdd(&cnt[r2.x], 0x10000u);
            atomicAdd(&cnt[c2.x], 1u);
            atomicAdd(&cnt[r2.y], 0x10000u);
            atomicAdd(&cnt[c2.y], 1u);
        } else if (t == E2 && odd) {
            atomicAdd(&cnt[rows[2 * E2]], 0x10000u);
            atomicAdd(&cnt[cols[2 * E2]], 1u);
        }
    } else if (b < ncount + ncvt) {
        // ---- cvt: one uint4 (8 bf16) per thread ----
        const long long i = (long long)(b - ncount) * 256 + threadIdx.x;
        if (i < totcvt) {
            const float4 a = x[i * 2];
            const float4 c = x[i * 2 + 1];
            uint4 o;
            o.x = bpack(a.x, a.y); o.y = bpack(a.z, a.w);
            o.z = bpack(c.x, c.y); o.w = bpack(c.z, c.w);
            xh[i] = o;
        }
    } else {
        // ---- wprep: lane l of entry (kq*8+jt) holds
        //      W[jt*16 + (l&15)][kq*32 + (l>>4)*8 .. +7] as bf16 ----
        const int t = (b - ncount - ncvt) * 256 + threadIdx.x;   // 0..2047
        const int l = t & 63;
        const int pair = t >> 6;
        const int kq = pair >> 3;
        const int jt = pair & 7;
        const int s = l & 15;
        const int g = l >> 4;
        const float* src = Wm + ((long long)(jt * 16 + s) << 7) + kq * 32 + g * 8;
        const float4 w0 = *(const float4*)(src);
        const float4 w1 = *(const float4*)(src + 4);
        uint4 o;
        o.x = bpack(w0.x, w0.y); o.y = bpack(w0.z, w0.w);
        o.z = bpack(w1.x, w1.y); o.w = bpack(w1.z, w1.w);
        wfrag[pair * 64 + l] = o;
    }
}

// ---- two-level exclusive scan of row-degrees (cnt >> 16) -> rp ----
__global__ __launch_bounds__(SCAN_B) void k_scan1(const uint32* __restrict__ cnt,
                                                  int* __restrict__ rp,
                                                  int* __restrict__ bsum, int n) {
    __shared__ int sh[SCAN_B];
    const int tid = threadIdx.x;
    const int i = blockIdx.x * SCAN_B + tid;
    int v = (i < n) ? (int)(cnt[i] >> 16) : 0;
    sh[tid] = v;
    __syncthreads();
    for (int off = 1; off < SCAN_B; off <<= 1) {
        int t = (tid >= off) ? sh[tid - off] : 0;
        __syncthreads();
        sh[tid] += t;
        __syncthreads();
    }
    if (i < n) rp[i] = sh[tid] - v;
    if (tid == SCAN_B - 1) bsum[blockIdx.x] = sh[SCAN_B - 1];
}

__global__ __launch_bounds__(SCAN_B) void k_scan2(int* __restrict__ bsum,
                                                  int* __restrict__ rp, int nb, int n) {
    __shared__ int sh[SCAN_B];
    const int tid = threadIdx.x;
    int v = (tid < nb) ? bsum[tid] : 0;
    sh[tid] = v;
    __syncthreads();
    for (int off = 1; off < SCAN_B; off <<= 1) {
        int t = (tid >= off) ? sh[tid - off] : 0;
        __syncthreads();
        sh[tid] += t;
        __syncthreads();
    }
    if (tid < nb) bsum[tid] = sh[tid] - v;
    if (tid == SCAN_B - 1) rp[n] = sh[SCAN_B - 1];
}

// final scan pass; unpack col-degree from cnt low half, overwrite cnt as dinv (f32)
__global__ void k_scan3(int* __restrict__ rp, int* __restrict__ cur,
                        const int* __restrict__ bsum, uint32* __restrict__ cnt, int n) {
    int i = blockIdx.x * blockDim.x + threadIdx.x;
    if (i < n) {
        int v = rp[i] + bsum[i >> 10];
        rp[i] = v;
        cur[i] = v;
        const uint32 c = cnt[i] & 0xffffu;
        ((float*)cnt)[i] = rsqrtf((float)(c + 1));
    }
}

// scatter edges into CSR slots as packed {col, weight_bits}; 2 edges per thread
__global__ void k_fill(const int2* __restrict__ rows2, const int2* __restrict__ cols2,
                       const float* __restrict__ dinv, int* __restrict__ cur,
                       int2* __restrict__ e8, int E2, int odd,
                       const int* __restrict__ rows, const int* __restrict__ cols) {
    int t = blockIdx.x * blockDim.x + threadIdx.x;
    if (t < E2) {
        const int2 r2 = rows2[t];
        const int2 c2 = cols2[t];
        const float w0 = dinv[r2.x] * dinv[c2.x];
        const float w1 = dinv[r2.y] * dinv[c2.y];
        const int p0 = atomicAdd(&cur[r2.x], 1);
        int2 q0; q0.x = c2.x; q0.y = __float_as_int(w0);
        e8[p0] = q0;
        const int p1 = atomicAdd(&cur[r2.y], 1);
        int2 q1; q1.x = c2.y; q1.y = __float_as_int(w1);
        e8[p1] = q1;
    } else if (t == E2 && odd) {
        const int r = rows[2 * E2], c = cols[2 * E2];
        const float w = dinv[r] * dinv[c];
        const int p = atomicAdd(&cur[r], 1);
        int2 q; q.x = c; q.y = __float_as_int(w);
        e8[p] = q;
    }
}

// out[r][:] = dinv[r]^2 * xin[r][:] + sum_e w_e * xin[col_e][:]
// ONE ROW PER WAVE: 4 edge-groups (l>>4) x 16 lanes (16B d-slice).
// Edge loop unrolled x2 -> up to 8 row-gathers in flight per wave.
// __shfl_xor(16/32) merges groups; group 0 adds self-term and stores bf16.
__global__ __launch_bounds__(256) void k_spmm(const uint4* __restrict__ xh,
                                              const int* __restrict__ rp,
                                              const int2* __restrict__ e8,
                                              const float* __restrict__ dinv,
                                              uint4* __restrict__ outh, int n) {
    const int row = blockIdx.x * 4 + (threadIdx.x >> 6);
    if (row >= n) return;
    const int l = threadIdx.x & 63;
    const int g = l >> 4;
    const int s = l & 15;

    float a0 = 0, a1 = 0, a2 = 0, a3 = 0, a4 = 0, a5 = 0, a6 = 0, a7 = 0;
    if (g == 0) {
        const float dv = dinv[row];
        const float sc = dv * dv;
        const uint4 sv = xh[(long long)row * 16 + s];
        a0 = sc * blo(sv.x); a1 = sc * bhi(sv.x);
        a2 = sc * blo(sv.y); a3 = sc * bhi(sv.y);
        a4 = sc * blo(sv.z); a5 = sc * bhi(sv.z);
        a6 = sc * blo(sv.w); a7 = sc * bhi(sv.w);
    }

    const int end = rp[row + 1];
    int e = rp[row] + g;
    for (; e + 4 < end; e += 8) {
        const int2 p0 = e8[e];
        const int2 p1 = e8[e + 4];
        const uint4 v0 = xh[(long long)p0.x * 16 + s];
        const uint4 v1 = xh[(long long)p1.x * 16 + s];
        const float w0 = __int_as_float(p0.y);
        const float w1 = __int_as_float(p1.y);
        a0 += w0 * blo(v0.x) + w1 * blo(v1.x);
        a1 += w0 * bhi(v0.x) + w1 * bhi(v1.x);
        a2 += w0 * blo(v0.y) + w1 * blo(v1.y);
        a3 += w0 * bhi(v0.y) + w1 * bhi(v1.y);
        a4 += w0 * blo(v0.z) + w1 * blo(v1.z);
        a5 += w0 * bhi(v0.z) + w1 * bhi(v1.z);
        a6 += w0 * blo(v0.w) + w1 * blo(v1.w);
        a7 += w0 * bhi(v0.w) + w1 * bhi(v1.w);
    }
    if (e < end) {
        const int2 p = e8[e];
        const float w = __int_as_float(p.y);
        const uint4 v = xh[(long long)p.x * 16 + s];
        a0 += w * blo(v.x); a1 += w * bhi(v.x);
        a2 += w * blo(v.y); a3 += w * bhi(v.y);
        a4 += w * blo(v.z); a5 += w * bhi(v.z);
        a6 += w * blo(v.w); a7 += w * bhi(v.w);
    }

    a0 += __shfl_xor(a0, 16); a1 += __shfl_xor(a1, 16);
    a2 += __shfl_xor(a2, 16); a3 += __shfl_xor(a3, 16);
    a4 += __shfl_xor(a4, 16); a5 += __shfl_xor(a5, 16);
    a6 += __shfl_xor(a6, 16); a7 += __shfl_xor(a7, 16);
    a0 += __shfl_xor(a0, 32); a1 += __shfl_xor(a1, 32);
    a2 += __shfl_xor(a2, 32); a3 += __shfl_xor(a3, 32);
    a4 += __shfl_xor(a4, 32); a5 += __shfl_xor(a5, 32);
    a6 += __shfl_xor(a6, 32); a7 += __shfl_xor(a7, 32);

    if (g == 0) {
        uint4 o;
        o.x = bpack(a0, a1); o.y = bpack(a2, a3);
        o.z = bpack(a4, a5); o.w = bpack(a6, a7);
        outh[(long long)row * 16 + s] = o;
    }
}

// C[r][:] = bf16(A[r][:]) @ bf16(W)^T + b via mfma_f32_16x16x32_bf16.
// Block = 4 waves x 64 rows = 256 rows, all 128 cols. NO LDS.
// Tail waves clamp to [n-64, n): duplicate stores of identical values, no OOB reads.
__global__ __launch_bounds__(256, 2) void k_gemm(const short8* __restrict__ A8,
                                                 const short8* __restrict__ wfrag,
                                                 const float* __restrict__ bias,
                                                 float* __restrict__ xout, int n) {
    const int wid = threadIdx.x >> 6;
    const int l = threadIdx.x & 63;
    const int ls = l & 15;
    const int lg = l >> 4;
    long long row0 = (long long)blockIdx.x * 256 + wid * 64;
    if (row0 + 64 > n) row0 = (long long)n - 64;

    float breg[8];
#pragma unroll
    for (int jt = 0; jt < 8; ++jt) breg[jt] = bias[jt * 16 + ls];

    f32x4 acc[4][8] = {};

#pragma unroll
    for (int kq = 0; kq < 4; ++kq) {
        short8 af[4];
#pragma unroll
        for (int m = 0; m < 4; ++m)
            af[m] = A8[(row0 + m * 16 + ls) * 16 + kq * 4 + lg];
#pragma unroll
        for (int jt = 0; jt < 8; ++jt) {
            const short8 bf = wfrag[(kq * 8 + jt) * 64 + l];
#pragma unroll
            for (int m = 0; m < 4; ++m)
                acc[m][jt] = __builtin_amdgcn_mfma_f32_16x16x32_bf16(
                    af[m], bf, acc[m][jt], 0, 0, 0);
        }
    }

#pragma unroll
    for (int m = 0; m < 4; ++m) {
#pragma unroll
        for (int q = 0; q < 4; ++q) {
            const long long row = row0 + m * 16 + lg * 4 + q;
            float* orow = xout + (row << 7);
#pragma unroll
            for (int jt = 0; jt < 8; ++jt)
                orow[jt * 16 + ls] = acc[m][jt][q] + breg[jt];
        }
    }
}

extern "C" void kernel_launch(void* const* d_in, const int* in_sizes, int n_in,
                              void* d_out, int out_size, void* d_ws, size_t ws_size,
                              hipStream_t stream) {
    const float* x = (const float*)d_in[0];
    const int* ei = (const int*)d_in[1];
    const float* Wm = (const float*)d_in[2];
    const float* bias = (const float*)d_in[3];
    float* out = (float*)d_out;

    const int n = in_sizes[0] / D;
    const int E = in_sizes[1] / 2;
    const int E2 = E >> 1;
    const int odd = E & 1;
    const int NB = (n + SCAN_B - 1) / SCAN_B;

    char* ws = (char*)d_ws;
    size_t off = 0;
    auto alloc = [&](long long bytes) {
        void* p = ws + off;
        off += (size_t)((bytes + 511) & ~511LL);
        return p;
    };
    uint32* cnt = (uint32*)alloc((long long)n * 4);    // packed hist -> dinv (f32)
    int* cur    = (int*)alloc((long long)n * 4);
    int* rp     = (int*)alloc((long long)(n + 1) * 4);
    int* bsum   = (int*)alloc((long long)SCAN_B * 4);
    int2* e8    = (int2*)alloc((long long)E * 8);
    uint4* xh   = (uint4*)alloc((long long)n * 256);   // bf16 x; reused as hop-2 output
    uint4* x1h  = (uint4*)alloc((long long)n * 256);   // bf16 hop-1 output
    uint4* wfrag= (uint4*)alloc(2048LL * 16);          // 32 KB B-fragments
    float* dinv = (float*)cnt;

    const int* rows = ei;
    const int* cols = ei + E;
    const int2* rows2 = (const int2*)rows;
    const int2* cols2 = (const int2*)cols;

    const int B = 256;
    const long long totcvt = (long long)n * 16;        // uint4s
    const int ncount = ceil_div_ll(E2 + 1, B);
    const int ncvt = ceil_div_ll(totcvt, B);

    k_init<<<ceil_div_ll(n, B), B, 0, stream>>>(cnt, n);
    // count (atomic-bound) || cvt (BW-bound) || wprep, one dispatch
    k_fused<<<ncount + ncvt + 8, B, 0, stream>>>(
        rows2, cols2, cnt, E2, odd, rows, cols,
        (const float4*)x, xh, totcvt, Wm, wfrag, ncount, ncvt);

    k_scan1<<<NB, SCAN_B, 0, stream>>>(cnt, rp, bsum, n);
    k_scan2<<<1, SCAN_B, 0, stream>>>(bsum, rp, NB, n);
    k_scan3<<<ceil_div_ll(n, B), B, 0, stream>>>(rp, cur, bsum, cnt, n);
    k_fill<<<ceil_div_ll(E2 + 1, B), B, 0, stream>>>(rows2, cols2, dinv, cur, e8, E2, odd, rows, cols);

    // hop 1: x1h = A_norm @ xh ; hop 2: xh = A_norm @ x1h  (xh dead after hop 1)
    k_spmm<<<ceil_div_ll(n, 4), B, 0, stream>>>(xh, rp, e8, dinv, x1h, n);
    k_spmm<<<ceil_div_ll(n, 4), B, 0, stream>>>(x1h, rp, e8, dinv, xh, n);

    k_gemm<<<ceil_div_ll(n, 256), B, 0, stream>>>(
        (const short8*)xh, (const short8*)wfrag, bias, out, n);
}

// Round 11
// 182.352 us; speedup vs baseline: 1.1906x; 1.1906x over previous
//
#include <hip/hip_runtime.h>

#define D 128
#define SCAN_B 1024

static inline int ceil_div_ll(long long a, int b) { return (int)((a + b - 1) / b); }

typedef unsigned int uint32;
typedef __attribute__((ext_vector_type(8))) short short8;   // 8 x bf16 (4 VGPRs)
typedef __attribute__((ext_vector_type(4))) float f32x4;    // MFMA C/D

__device__ __forceinline__ float blo(uint32 u) { return __uint_as_float(u << 16); }
__device__ __forceinline__ float bhi(uint32 u) { return __uint_as_float(u & 0xffff0000u); }
__device__ __forceinline__ uint32 bpack(float a, float b) {   // 2x f32 -> bf16x2 RTNE
    uint32 ua = __float_as_uint(a), ub = __float_as_uint(b);
    ua += 0x7fffu + ((ua >> 16) & 1u);
    ub += 0x7fffu + ((ub >> 16) & 1u);
    return (ua >> 16) | (ub & 0xffff0000u);
}

// zero packed histogram
__global__ void k_init(uint32* __restrict__ cnt, int n) {
    int i = blockIdx.x * blockDim.x + threadIdx.x;
    if (i < n) cnt[i] = 0;
}

// FUSED, roles INTERLEAVED (1 count : 5 cvt per group of 6 blocks, then cvt
// remainder, then 8 wprep blocks). Count emits per-edge row-rank (old>>16)
// so the CSR fill needs no atomics.
__global__ __launch_bounds__(256) void k_fused(
        const int2* __restrict__ rows2, const int2* __restrict__ cols2,
        uint32* __restrict__ cnt, ushort* __restrict__ rank16, int E2, int odd,
        const int* __restrict__ rows, const int* __restrict__ cols,
        const float4* __restrict__ x, uint4* __restrict__ xh, long long totcvt,
        const float* __restrict__ Wm, uint4* __restrict__ wfrag,
        int ncount, int ncvt, int cvtLeft) {
    const int b = blockIdx.x;
    int role, idx;
    if (b < 6 * ncount) {
        const int g = b / 6, p = b - g * 6;
        if (p == 0) { role = 0; idx = g; }
        else        { role = 1; idx = g * 5 + (p - 1); }
    } else if (b < 6 * ncount + cvtLeft) {
        role = 1; idx = 5 * ncount + (b - 6 * ncount);
    } else {
        role = 2; idx = b - 6 * ncount - cvtLeft;
    }

    if (role == 0) {
        // ---- packed histogram + rank emit ----
        const int t = idx * 256 + threadIdx.x;
        if (t < E2) {
            const int2 r2 = rows2[t];
            const int2 c2 = cols2[t];
            const uint32 o0 = atomicAdd(&cnt[r2.x], 0x10000u);
            atomicAdd(&cnt[c2.x], 1u);
            const uint32 o1 = atomicAdd(&cnt[r2.y], 0x10000u);
            atomicAdd(&cnt[c2.y], 1u);
            ushort2 rk;
            rk.x = (ushort)(o0 >> 16);
            rk.y = (ushort)(o1 >> 16);
            *(ushort2*)(rank16 + 2 * t) = rk;
        } else if (t == E2 && odd) {
            const uint32 o = atomicAdd(&cnt[rows[2 * E2]], 0x10000u);
            atomicAdd(&cnt[cols[2 * E2]], 1u);
            rank16[2 * E2] = (ushort)(o >> 16);
        }
    } else if (role == 1) {
        // ---- cvt: one uint4 (8 bf16) per thread ----
        if (idx >= ncvt) return;
        const long long i = (long long)idx * 256 + threadIdx.x;
        if (i < totcvt) {
            const float4 a = x[i * 2];
            const float4 c = x[i * 2 + 1];
            uint4 o;
            o.x = bpack(a.x, a.y); o.y = bpack(a.z, a.w);
            o.z = bpack(c.x, c.y); o.w = bpack(c.z, c.w);
            xh[i] = o;
        }
    } else {
        // ---- wprep: lane l of entry (kq*8+jt) holds
        //      W[jt*16 + (l&15)][kq*32 + (l>>4)*8 .. +7] as bf16 ----
        const int t = idx * 256 + threadIdx.x;   // 0..2047
        if (t >= 2048) return;
        const int l = t & 63;
        const int pair = t >> 6;
        const int kq = pair >> 3;
        const int jt = pair & 7;
        const int s = l & 15;
        const int g = l >> 4;
        const float* src = Wm + ((long long)(jt * 16 + s) << 7) + kq * 32 + g * 8;
        const float4 w0 = *(const float4*)(src);
        const float4 w1 = *(const float4*)(src + 4);
        uint4 o;
        o.x = bpack(w0.x, w0.y); o.y = bpack(w0.z, w0.w);
        o.z = bpack(w1.x, w1.y); o.w = bpack(w1.z, w1.w);
        wfrag[pair * 64 + l] = o;
    }
}

// ---- two-level exclusive scan of row-degrees (cnt >> 16) -> rp ----
__global__ __launch_bounds__(SCAN_B) void k_scan1(const uint32* __restrict__ cnt,
                                                  int* __restrict__ rp,
                                                  int* __restrict__ bsum, int n) {
    __shared__ int sh[SCAN_B];
    const int tid = threadIdx.x;
    const int i = blockIdx.x * SCAN_B + tid;
    int v = (i < n) ? (int)(cnt[i] >> 16) : 0;
    sh[tid] = v;
    __syncthreads();
    for (int off = 1; off < SCAN_B; off <<= 1) {
        int t = (tid >= off) ? sh[tid - off] : 0;
        __syncthreads();
        sh[tid] += t;
        __syncthreads();
    }
    if (i < n) rp[i] = sh[tid] - v;
    if (tid == SCAN_B - 1) bsum[blockIdx.x] = sh[SCAN_B - 1];
}

__global__ __launch_bounds__(SCAN_B) void k_scan2(int* __restrict__ bsum,
                                                  int* __restrict__ rp, int nb, int n) {
    __shared__ int sh[SCAN_B];
    const int tid = threadIdx.x;
    int v = (tid < nb) ? bsum[tid] : 0;
    sh[tid] = v;
    __syncthreads();
    for (int off = 1; off < SCAN_B; off <<= 1) {
        int t = (tid >= off) ? sh[tid - off] : 0;
        __syncthreads();
        sh[tid] += t;
        __syncthreads();
    }
    if (tid < nb) bsum[tid] = sh[tid] - v;
    if (tid == SCAN_B - 1) rp[n] = sh[SCAN_B - 1];
}

// final scan pass; unpack col-degree from cnt low half, overwrite cnt as dinv (f32)
__global__ void k_scan3(int* __restrict__ rp, const int* __restrict__ bsum,
                        uint32* __restrict__ cnt, int n) {
    int i = blockIdx.x * blockDim.x + threadIdx.x;
    if (i < n) {
        rp[i] += bsum[i >> 10];
        const uint32 c = cnt[i] & 0xffffu;
        ((float*)cnt)[i] = rsqrtf((float)(c + 1));
    }
}

// ATOMIC-FREE CSR fill: slot = rp[r] + rank16[e]; 2 edges per thread
__global__ void k_fill(const int2* __restrict__ rows2, const int2* __restrict__ cols2,
                       const ushort* __restrict__ rank16,
                       const float* __restrict__ dinv, const int* __restrict__ rp,
                       int2* __restrict__ e8, int E2, int odd,
                       const int* __restrict__ rows, const int* __restrict__ cols) {
    int t = blockIdx.x * blockDim.x + threadIdx.x;
    if (t < E2) {
        const int2 r2 = rows2[t];
        const int2 c2 = cols2[t];
        const ushort2 rk = *(const ushort2*)(rank16 + 2 * t);
        const float w0 = dinv[r2.x] * dinv[c2.x];
        const float w1 = dinv[r2.y] * dinv[c2.y];
        int2 q0; q0.x = c2.x; q0.y = __float_as_int(w0);
        int2 q1; q1.x = c2.y; q1.y = __float_as_int(w1);
        e8[rp[r2.x] + rk.x] = q0;
        e8[rp[r2.y] + rk.y] = q1;
    } else if (t == E2 && odd) {
        const int r = rows[2 * E2], c = cols[2 * E2];
        const float w = dinv[r] * dinv[c];
        int2 q; q.x = c; q.y = __float_as_int(w);
        e8[rp[r] + rank16[2 * E2]] = q;
    }
}

// out[r][:] = dinv[r]^2 * xin[r][:] + sum_e w_e * xin[col_e][:]
// ONE ROW PER 64-LANE WAVE, 4 B (bf16x2) per lane. Descriptor loads are
// wave-uniform (-> scalar cache); 4 independent gathers per round; tail
// handled by clamped-index + zeroed-weight predication. No shuffles.
__global__ __launch_bounds__(256) void k_spmm(const uint32* __restrict__ xh,
                                              const int* __restrict__ rp,
                                              const int2* __restrict__ e8,
                                              const float* __restrict__ dinv,
                                              uint32* __restrict__ outh, int n) {
    const int row = blockIdx.x * 4 + (threadIdx.x >> 6);
    if (row >= n) return;
    const int l = threadIdx.x & 63;

    const float dv = dinv[row];
    const float sc = dv * dv;
    const uint32 sv = xh[(long long)row * 64 + l];
    float alo = sc * blo(sv);
    float ahi = sc * bhi(sv);

    int e = rp[row];
    const int end = rp[row + 1];
    while (e < end) {
        const int last = end - 1;
        const int i1 = (e + 1 < last) ? e + 1 : last;
        const int i2 = (e + 2 < last) ? e + 2 : last;
        const int i3 = (e + 3 < last) ? e + 3 : last;
        const int2 p0 = e8[e];
        const int2 p1 = e8[i1];
        const int2 p2 = e8[i2];
        const int2 p3 = e8[i3];
        const uint32 v0 = xh[(long long)p0.x * 64 + l];
        const uint32 v1 = xh[(long long)p1.x * 64 + l];
        const uint32 v2 = xh[(long long)p2.x * 64 + l];
        const uint32 v3 = xh[(long long)p3.x * 64 + l];
        const float w0 = __int_as_float(p0.y);
        const float w1 = (e + 1 <= last) ? __int_as_float(p1.y) : 0.0f;
        const float w2 = (e + 2 <= last) ? __int_as_float(p2.y) : 0.0f;
        const float w3 = (e + 3 <= last) ? __int_as_float(p3.y) : 0.0f;
        alo += w0 * blo(v0) + w1 * blo(v1) + w2 * blo(v2) + w3 * blo(v3);
        ahi += w0 * bhi(v0) + w1 * bhi(v1) + w2 * bhi(v2) + w3 * bhi(v3);
        e += 4;
    }

    outh[(long long)row * 64 + l] = bpack(alo, ahi);
}

// C[r][:] = bf16(A[r][:]) @ bf16(W)^T + b via mfma_f32_16x16x32_bf16.
// Block = 4 waves x 64 rows = 256 rows, all 128 cols. NO LDS.
// Tail waves clamp to [n-64, n): duplicate stores of identical values, no OOB reads.
__global__ __launch_bounds__(256, 2) void k_gemm(const short8* __restrict__ A8,
                                                 const short8* __restrict__ wfrag,
                                                 const float* __restrict__ bias,
                                                 float* __restrict__ xout, int n) {
    const int wid = threadIdx.x >> 6;
    const int l = threadIdx.x & 63;
    const int ls = l & 15;
    const int lg = l >> 4;
    long long row0 = (long long)blockIdx.x * 256 + wid * 64;
    if (row0 + 64 > n) row0 = (long long)n - 64;

    float breg[8];
#pragma unroll
    for (int jt = 0; jt < 8; ++jt) breg[jt] = bias[jt * 16 + ls];

    f32x4 acc[4][8] = {};

#pragma unroll
    for (int kq = 0; kq < 4; ++kq) {
        short8 af[4];
#pragma unroll
        for (int m = 0; m < 4; ++m)
            af[m] = A8[(row0 + m * 16 + ls) * 16 + kq * 4 + lg];
#pragma unroll
        for (int jt = 0; jt < 8; ++jt) {
            const short8 bf = wfrag[(kq * 8 + jt) * 64 + l];
#pragma unroll
            for (int m = 0; m < 4; ++m)
                acc[m][jt] = __builtin_amdgcn_mfma_f32_16x16x32_bf16(
                    af[m], bf, acc[m][jt], 0, 0, 0);
        }
    }

#pragma unroll
    for (int m = 0; m < 4; ++m) {
#pragma unroll
        for (int q = 0; q < 4; ++q) {
            const long long row = row0 + m * 16 + lg * 4 + q;
            float* orow = xout + (row << 7);
#pragma unroll
            for (int jt = 0; jt < 8; ++jt)
                orow[jt * 16 + ls] = acc[m][jt][q] + breg[jt];
        }
    }
}

extern "C" void kernel_launch(void* const* d_in, const int* in_sizes, int n_in,
                              void* d_out, int out_size, void* d_ws, size_t ws_size,
                              hipStream_t stream) {
    const float* x = (const float*)d_in[0];
    const int* ei = (const int*)d_in[1];
    const float* Wm = (const float*)d_in[2];
    const float* bias = (const float*)d_in[3];
    float* out = (float*)d_out;

    const int n = in_sizes[0] / D;
    const int E = in_sizes[1] / 2;
    const int E2 = E >> 1;
    const int odd = E & 1;
    const int NB = (n + SCAN_B - 1) / SCAN_B;

    char* ws = (char*)d_ws;
    size_t off = 0;
    auto alloc = [&](long long bytes) {
        void* p = ws + off;
        off += (size_t)((bytes + 511) & ~511LL);
        return p;
    };
    uint32* cnt   = (uint32*)alloc((long long)n * 4);   // packed hist -> dinv (f32)
    int* rp       = (int*)alloc((long long)(n + 1) * 4);
    int* bsum     = (int*)alloc((long long)SCAN_B * 4);
    ushort* rank16= (ushort*)alloc((long long)E * 2);   // per-edge row rank
    int2* e8      = (int2*)alloc((long long)E * 8);
    uint4* xh     = (uint4*)alloc((long long)n * 256);  // bf16 x; reused as hop-2 output
    uint4* x1h    = (uint4*)alloc((long long)n * 256);  // bf16 hop-1 output
    uint4* wfrag  = (uint4*)alloc(2048LL * 16);         // 32 KB B-fragments
    float* dinv   = (float*)cnt;

    const int* rows = ei;
    const int* cols = ei + E;
    const int2* rows2 = (const int2*)rows;
    const int2* cols2 = (const int2*)cols;

    const int B = 256;
    const long long totcvt = (long long)n * 16;         // uint4s
    const int ncount = ceil_div_ll(E2 + 1, B);
    const int ncvt = ceil_div_ll(totcvt, B);
    const int cvtLeft = (ncvt > 5 * ncount) ? (ncvt - 5 * ncount) : 0;
    const int grid_fused = 6 * ncount + cvtLeft + 8;

    k_init<<<ceil_div_ll(n, B), B, 0, stream>>>(cnt, n);
    // count (atomic-bound, emits ranks) || cvt (BW-bound) || wprep — interleaved
    k_fused<<<grid_fused, B, 0, stream>>>(
        rows2, cols2, cnt, rank16, E2, odd, rows, cols,
        (const float4*)x, xh, totcvt, Wm, wfrag, ncount, ncvt, cvtLeft);

    k_scan1<<<NB, SCAN_B, 0, stream>>>(cnt, rp, bsum, n);
    k_scan2<<<1, SCAN_B, 0, stream>>>(bsum, rp, NB, n);
    k_scan3<<<ceil_div_ll(n, B), B, 0, stream>>>(rp, bsum, cnt, n);
    // atomic-free CSR fill
    k_fill<<<ceil_div_ll(E2 + 1, B), B, 0, stream>>>(
        rows2, cols2, rank16, dinv, rp, e8, E2, odd, rows, cols);

    // hop 1: x1h = A_norm @ xh ; hop 2: xh = A_norm @ x1h  (xh dead after hop 1)
    k_spmm<<<ceil_div_ll(n, 4), B, 0, stream>>>(
        (const uint32*)xh, rp, e8, dinv, (uint32*)x1h, n);
    k_spmm<<<ceil_div_ll(n, 4), B, 0, stream>>>(
        (const uint32*)x1h, rp, e8, dinv, (uint32*)xh, n);

    k_gemm<<<ceil_div_ll(n, 256), B, 0, stream>>>(
        (const short8*)xh, (const short8*)wfrag, bias, out, n);
}

// Round 12
// 176.453 us; speedup vs baseline: 1.2304x; 1.0334x over previous
//
#include <hip/hip_runtime.h>

#define D 128
#define SCAN_B 1024

static inline int ceil_div_ll(long long a, int b) { return (int)((a + b - 1) / b); }

typedef unsigned int uint32;
typedef __attribute__((ext_vector_type(8))) short short8;   // 8 x bf16 (4 VGPRs)
typedef __attribute__((ext_vector_type(4))) float f32x4;    // MFMA C/D

__device__ __forceinline__ float blo(uint32 u) { return __uint_as_float(u << 16); }
__device__ __forceinline__ float bhi(uint32 u) { return __uint_as_float(u & 0xffff0000u); }
__device__ __forceinline__ uint32 bpack(float a, float b) {   // 2x f32 -> bf16x2 RTNE
    uint32 ua = __float_as_uint(a), ub = __float_as_uint(b);
    ua += 0x7fffu + ((ua >> 16) & 1u);
    ub += 0x7fffu + ((ub >> 16) & 1u);
    return (ua >> 16) | (ub & 0xffff0000u);
}

// zero packed histogram
__global__ void k_init(uint32* __restrict__ cnt, int n) {
    int i = blockIdx.x * blockDim.x + threadIdx.x;
    if (i < n) cnt[i] = 0;
}

// FUSED, roles INTERLEAVED (1 count : 5 cvt per 6 blocks, cvt remainder, 8 wprep).
// Count emits per-edge row-rank so CSR fill needs no atomics.
__global__ __launch_bounds__(256) void k_fused(
        const int2* __restrict__ rows2, const int2* __restrict__ cols2,
        uint32* __restrict__ cnt, ushort* __restrict__ rank16, int E2, int odd,
        const int* __restrict__ rows, const int* __restrict__ cols,
        const float4* __restrict__ x, uint4* __restrict__ xh, long long totcvt,
        const float* __restrict__ Wm, uint4* __restrict__ wfrag,
        int ncount, int ncvt, int cvtLeft) {
    const int b = blockIdx.x;
    int role, idx;
    if (b < 6 * ncount) {
        const int g = b / 6, p = b - g * 6;
        if (p == 0) { role = 0; idx = g; }
        else        { role = 1; idx = g * 5 + (p - 1); }
    } else if (b < 6 * ncount + cvtLeft) {
        role = 1; idx = 5 * ncount + (b - 6 * ncount);
    } else {
        role = 2; idx = b - 6 * ncount - cvtLeft;
    }

    if (role == 0) {
        const int t = idx * 256 + threadIdx.x;
        if (t < E2) {
            const int2 r2 = rows2[t];
            const int2 c2 = cols2[t];
            const uint32 o0 = atomicAdd(&cnt[r2.x], 0x10000u);
            atomicAdd(&cnt[c2.x], 1u);
            const uint32 o1 = atomicAdd(&cnt[r2.y], 0x10000u);
            atomicAdd(&cnt[c2.y], 1u);
            ushort2 rk;
            rk.x = (ushort)(o0 >> 16);
            rk.y = (ushort)(o1 >> 16);
            *(ushort2*)(rank16 + 2 * t) = rk;
        } else if (t == E2 && odd) {
            const uint32 o = atomicAdd(&cnt[rows[2 * E2]], 0x10000u);
            atomicAdd(&cnt[cols[2 * E2]], 1u);
            rank16[2 * E2] = (ushort)(o >> 16);
        }
    } else if (role == 1) {
        if (idx >= ncvt) return;
        const long long i = (long long)idx * 256 + threadIdx.x;
        if (i < totcvt) {
            const float4 a = x[i * 2];
            const float4 c = x[i * 2 + 1];
            uint4 o;
            o.x = bpack(a.x, a.y); o.y = bpack(a.z, a.w);
            o.z = bpack(c.x, c.y); o.w = bpack(c.z, c.w);
            xh[i] = o;
        }
    } else {
        // wprep: lane l of entry (kq*8+jt) holds W[jt*16+(l&15)][kq*32+(l>>4)*8..+7]
        const int t = idx * 256 + threadIdx.x;
        if (t >= 2048) return;
        const int l = t & 63;
        const int pair = t >> 6;
        const int kq = pair >> 3;
        const int jt = pair & 7;
        const int s = l & 15;
        const int g = l >> 4;
        const float* src = Wm + ((long long)(jt * 16 + s) << 7) + kq * 32 + g * 8;
        const float4 w0 = *(const float4*)(src);
        const float4 w1 = *(const float4*)(src + 4);
        uint4 o;
        o.x = bpack(w0.x, w0.y); o.y = bpack(w0.z, w0.w);
        o.z = bpack(w1.x, w1.y); o.w = bpack(w1.z, w1.w);
        wfrag[pair * 64 + l] = o;
    }
}

// ---- two-level exclusive scan of row-degrees (cnt >> 16) -> rp ----
__global__ __launch_bounds__(SCAN_B) void k_scan1(const uint32* __restrict__ cnt,
                                                  int* __restrict__ rp,
                                                  int* __restrict__ bsum, int n) {
    __shared__ int sh[SCAN_B];
    const int tid = threadIdx.x;
    const int i = blockIdx.x * SCAN_B + tid;
    int v = (i < n) ? (int)(cnt[i] >> 16) : 0;
    sh[tid] = v;
    __syncthreads();
    for (int off = 1; off < SCAN_B; off <<= 1) {
        int t = (tid >= off) ? sh[tid - off] : 0;
        __syncthreads();
        sh[tid] += t;
        __syncthreads();
    }
    if (i < n) rp[i] = sh[tid] - v;
    if (tid == SCAN_B - 1) bsum[blockIdx.x] = sh[SCAN_B - 1];
}

__global__ __launch_bounds__(SCAN_B) void k_scan2(int* __restrict__ bsum,
                                                  int* __restrict__ rp, int nb, int n) {
    __shared__ int sh[SCAN_B];
    const int tid = threadIdx.x;
    int v = (tid < nb) ? bsum[tid] : 0;
    sh[tid] = v;
    __syncthreads();
    for (int off = 1; off < SCAN_B; off <<= 1) {
        int t = (tid >= off) ? sh[tid - off] : 0;
        __syncthreads();
        sh[tid] += t;
        __syncthreads();
    }
    if (tid < nb) bsum[tid] = sh[tid] - v;
    if (tid == SCAN_B - 1) rp[n] = sh[SCAN_B - 1];
}

// finalize rp only (dinv now produced in the zscale role)
__global__ void k_scan3(int* __restrict__ rp, const int* __restrict__ bsum, int n) {
    int i = blockIdx.x * blockDim.x + threadIdx.x;
    if (i < n) rp[i] += bsum[i >> 10];
}

// FUSED: [0,nfill): atomic-free CSR fill (col only, 4 B/edge)
//        [nfill,+nzs): z0 = dinv * xh in place; also writes dinv[] (f32)
__global__ __launch_bounds__(256) void k_fillz(
        const int2* __restrict__ rows2, const int2* __restrict__ cols2,
        const ushort* __restrict__ rank16, const int* __restrict__ rp,
        int* __restrict__ e4, int E2, int odd,
        const int* __restrict__ rows, const int* __restrict__ cols,
        const uint32* __restrict__ cnt, float* __restrict__ dinv,
        uint4* __restrict__ xh, long long totz, int nfill) {
    const int b = blockIdx.x;
    if (b < nfill) {
        const int t = b * 256 + threadIdx.x;
        if (t < E2) {
            const int2 r2 = rows2[t];
            const int2 c2 = cols2[t];
            const ushort2 rk = *(const ushort2*)(rank16 + 2 * t);
            e4[rp[r2.x] + rk.x] = c2.x;
            e4[rp[r2.y] + rk.y] = c2.y;
        } else if (t == E2 && odd) {
            e4[rp[rows[2 * E2]] + rank16[2 * E2]] = cols[2 * E2];
        }
    } else {
        const long long idx = (long long)(b - nfill) * 256 + threadIdx.x;
        if (idx < totz) {
            const int i = (int)(idx >> 4);
            const float dv = rsqrtf((float)((cnt[i] & 0xffffu) + 1u));
            uint4 v = xh[idx];
            v.x = bpack(dv * blo(v.x), dv * bhi(v.x));
            v.y = bpack(dv * blo(v.y), dv * bhi(v.y));
            v.z = bpack(dv * blo(v.z), dv * bhi(v.z));
            v.w = bpack(dv * blo(v.w), dv * bhi(v.w));
            xh[idx] = v;
            if ((idx & 15) == 0) dinv[i] = dv;
        }
    }
}

// z-space hop: u[r] = z[r] + sum_{c in N(r)} z[c];  out[r] = dinv[r]^PW * u[r]
// ONE ROW PER 64-LANE WAVE, 4 B (bf16x2)/lane. Unweighted gathers, unroll 8
// (clamped-index + predicated add) -> most rows need ONE latency round.
template <int PW>
__global__ __launch_bounds__(256) void k_spmm(const uint32* __restrict__ xh,
                                              const int* __restrict__ rp,
                                              const int* __restrict__ e4,
                                              const float* __restrict__ dinv,
                                              uint32* __restrict__ outh, int n) {
    const int row = blockIdx.x * 4 + (threadIdx.x >> 6);
    if (row >= n) return;
    const int l = threadIdx.x & 63;

    const float dv = dinv[row];
    const float sc = (PW == 2) ? dv * dv : dv;

    const uint32 sv = xh[(long long)row * 64 + l];
    float alo = blo(sv);
    float ahi = bhi(sv);

    int e = rp[row];
    const int end = rp[row + 1];
    while (e < end) {
        const int last = end - 1;
        int c[8];
#pragma unroll
        for (int k = 0; k < 8; ++k) {
            const int i = (e + k < last) ? e + k : last;
            c[k] = e4[i];
        }
        uint32 v[8];
#pragma unroll
        for (int k = 0; k < 8; ++k) v[k] = xh[(long long)c[k] * 64 + l];
#pragma unroll
        for (int k = 0; k < 8; ++k) {
            const float w = (e + k <= end - 1) ? 1.0f : 0.0f;
            alo += w * blo(v[k]);
            ahi += w * bhi(v[k]);
        }
        e += 8;
    }

    outh[(long long)row * 64 + l] = bpack(sc * alo, sc * ahi);
}

// C[r][:] = bf16(A[r][:]) @ bf16(W)^T + b via mfma_f32_16x16x32_bf16.
// Block = 4 waves; wave = 64 rows x 64 cols (acc 64 VGPR) -> 4 blocks/CU.
// Tail waves clamp to [n-64, n): duplicate identical stores, no OOB reads.
__global__ __launch_bounds__(256, 4) void k_gemm(const short8* __restrict__ A8,
                                                 const short8* __restrict__ wfrag,
                                                 const float* __restrict__ bias,
                                                 float* __restrict__ xout, int n) {
    const int wid = threadIdx.x >> 6;
    const int rg = wid >> 1;           // row group (0/1): 64 rows each
    const int cg = wid & 1;            // col group (0/1): 64 cols each
    const int l = threadIdx.x & 63;
    const int ls = l & 15;
    const int lg = l >> 4;
    long long row0 = (long long)blockIdx.x * 128 + rg * 64;
    if (row0 + 64 > n) row0 = (long long)n - 64;

    float breg[4];
#pragma unroll
    for (int jt = 0; jt < 4; ++jt) breg[jt] = bias[cg * 64 + jt * 16 + ls];

    f32x4 acc[4][4] = {};

#pragma unroll
    for (int kq = 0; kq < 4; ++kq) {
        short8 af[4];
#pragma unroll
        for (int m = 0; m < 4; ++m)
            af[m] = A8[(row0 + m * 16 + ls) * 16 + kq * 4 + lg];
#pragma unroll
        for (int jt = 0; jt < 4; ++jt) {
            const short8 bf = wfrag[(kq * 8 + cg * 4 + jt) * 64 + l];
#pragma unroll
            for (int m = 0; m < 4; ++m)
                acc[m][jt] = __builtin_amdgcn_mfma_f32_16x16x32_bf16(
                    af[m], bf, acc[m][jt], 0, 0, 0);
        }
    }

#pragma unroll
    for (int m = 0; m < 4; ++m) {
#pragma unroll
        for (int q = 0; q < 4; ++q) {
            const long long row = row0 + m * 16 + lg * 4 + q;
            float* orow = xout + (row << 7) + cg * 64;
#pragma unroll
            for (int jt = 0; jt < 4; ++jt)
                orow[jt * 16 + ls] = acc[m][jt][q] + breg[jt];
        }
    }
}

extern "C" void kernel_launch(void* const* d_in, const int* in_sizes, int n_in,
                              void* d_out, int out_size, void* d_ws, size_t ws_size,
                              hipStream_t stream) {
    const float* x = (const float*)d_in[0];
    const int* ei = (const int*)d_in[1];
    const float* Wm = (const float*)d_in[2];
    const float* bias = (const float*)d_in[3];
    float* out = (float*)d_out;

    const int n = in_sizes[0] / D;
    const int E = in_sizes[1] / 2;
    const int E2 = E >> 1;
    const int odd = E & 1;
    const int NB = (n + SCAN_B - 1) / SCAN_B;

    char* ws = (char*)d_ws;
    size_t off = 0;
    auto alloc = [&](long long bytes) {
        void* p = ws + off;
        off += (size_t)((bytes + 511) & ~511LL);
        return p;
    };
    uint32* cnt   = (uint32*)alloc((long long)n * 4);   // packed degree histogram
    int* rp       = (int*)alloc((long long)(n + 1) * 4);
    int* bsum     = (int*)alloc((long long)SCAN_B * 4);
    ushort* rank16= (ushort*)alloc((long long)E * 2);   // per-edge row rank
    int* e4       = (int*)alloc((long long)E * 4);      // CSR col only
    float* dinv   = (float*)alloc((long long)n * 4);
    uint4* xh     = (uint4*)alloc((long long)n * 256);  // bf16 x -> z0 -> hop2 out
    uint4* x1h    = (uint4*)alloc((long long)n * 256);  // bf16 z1
    uint4* wfrag  = (uint4*)alloc(2048LL * 16);         // 32 KB B-fragments

    const int* rows = ei;
    const int* cols = ei + E;
    const int2* rows2 = (const int2*)rows;
    const int2* cols2 = (const int2*)cols;

    const int B = 256;
    const long long totcvt = (long long)n * 16;         // uint4s
    const int ncount = ceil_div_ll(E2 + 1, B);
    const int ncvt = ceil_div_ll(totcvt, B);
    const int cvtLeft = (ncvt > 5 * ncount) ? (ncvt - 5 * ncount) : 0;
    const int grid_fused = 6 * ncount + cvtLeft + 8;
    const int nfill = ceil_div_ll(E2 + 1, B);
    const int nzs = ceil_div_ll(totcvt, B);

    k_init<<<ceil_div_ll(n, B), B, 0, stream>>>(cnt, n);
    k_fused<<<grid_fused, B, 0, stream>>>(
        rows2, cols2, cnt, rank16, E2, odd, rows, cols,
        (const float4*)x, xh, totcvt, Wm, wfrag, ncount, ncvt, cvtLeft);

    k_scan1<<<NB, SCAN_B, 0, stream>>>(cnt, rp, bsum, n);
    k_scan2<<<1, SCAN_B, 0, stream>>>(bsum, rp, NB, n);
    k_scan3<<<ceil_div_ll(n, B), B, 0, stream>>>(rp, bsum, n);
    // CSR fill (atomic-free, col-only) || z0 = dinv*x (in place) + dinv write
    k_fillz<<<nfill + nzs, B, 0, stream>>>(
        rows2, cols2, rank16, rp, e4, E2, odd, rows, cols,
        cnt, dinv, xh, totcvt, nfill);

    // hop 1 (z1 = dinv^2 * (z0 + sum z0)), hop 2 (x2 = dinv * (z1 + sum z1))
    k_spmm<2><<<ceil_div_ll(n, 4), B, 0, stream>>>(
        (const uint32*)xh, rp, e4, dinv, (uint32*)x1h, n);
    k_spmm<1><<<ceil_div_ll(n, 4), B, 0, stream>>>(
        (const uint32*)x1h, rp, e4, dinv, (uint32*)xh, n);

    k_gemm<<<ceil_div_ll(n, 128), B, 0, stream>>>(
        (const short8*)xh, (const short8*)wfrag, bias, out, n);
}

// Round 13
// 174.200 us; speedup vs baseline: 1.2463x; 1.0129x over previous
//
#include <hip/hip_runtime.h>

#define D 128
#define SCAN_B 1024

static inline int ceil_div_ll(long long a, int b) { return (int)((a + b - 1) / b); }

typedef unsigned int uint32;
typedef __attribute__((ext_vector_type(8))) short short8;   // 8 x bf16 (4 VGPRs)
typedef __attribute__((ext_vector_type(4))) float f32x4;    // MFMA C/D

__device__ __forceinline__ float blo(uint32 u) { return __uint_as_float(u << 16); }
__device__ __forceinline__ float bhi(uint32 u) { return __uint_as_float(u & 0xffff0000u); }
__device__ __forceinline__ uint32 bpack(float a, float b) {   // 2x f32 -> bf16x2 RTNE
    uint32 ua = __float_as_uint(a), ub = __float_as_uint(b);
    ua += 0x7fffu + ((ua >> 16) & 1u);
    ub += 0x7fffu + ((ub >> 16) & 1u);
    return (ua >> 16) | (ub & 0xffff0000u);
}

// zero packed histogram
__global__ void k_init(uint32* __restrict__ cnt, int n) {
    int i = blockIdx.x * blockDim.x + threadIdx.x;
    if (i < n) cnt[i] = 0;
}

// FUSED, roles INTERLEAVED (1 count : 5 cvt per 6 blocks, cvt remainder, 8 wprep).
// Count emits per-edge row-rank so CSR fill needs no atomics.
__global__ __launch_bounds__(256) void k_fused(
        const int2* __restrict__ rows2, const int2* __restrict__ cols2,
        uint32* __restrict__ cnt, ushort* __restrict__ rank16, int E2, int odd,
        const int* __restrict__ rows, const int* __restrict__ cols,
        const float4* __restrict__ x, uint4* __restrict__ xh, long long totcvt,
        const float* __restrict__ Wm, uint4* __restrict__ wfrag,
        int ncount, int ncvt, int cvtLeft) {
    const int b = blockIdx.x;
    int role, idx;
    if (b < 6 * ncount) {
        const int g = b / 6, p = b - g * 6;
        if (p == 0) { role = 0; idx = g; }
        else        { role = 1; idx = g * 5 + (p - 1); }
    } else if (b < 6 * ncount + cvtLeft) {
        role = 1; idx = 5 * ncount + (b - 6 * ncount);
    } else {
        role = 2; idx = b - 6 * ncount - cvtLeft;
    }

    if (role == 0) {
        const int t = idx * 256 + threadIdx.x;
        if (t < E2) {
            const int2 r2 = rows2[t];
            const int2 c2 = cols2[t];
            const uint32 o0 = atomicAdd(&cnt[r2.x], 0x10000u);
            atomicAdd(&cnt[c2.x], 1u);
            const uint32 o1 = atomicAdd(&cnt[r2.y], 0x10000u);
            atomicAdd(&cnt[c2.y], 1u);
            ushort2 rk;
            rk.x = (ushort)(o0 >> 16);
            rk.y = (ushort)(o1 >> 16);
            *(ushort2*)(rank16 + 2 * t) = rk;
        } else if (t == E2 && odd) {
            const uint32 o = atomicAdd(&cnt[rows[2 * E2]], 0x10000u);
            atomicAdd(&cnt[cols[2 * E2]], 1u);
            rank16[2 * E2] = (ushort)(o >> 16);
        }
    } else if (role == 1) {
        if (idx >= ncvt) return;
        const long long i = (long long)idx * 256 + threadIdx.x;
        if (i < totcvt) {
            const float4 a = x[i * 2];
            const float4 c = x[i * 2 + 1];
            uint4 o;
            o.x = bpack(a.x, a.y); o.y = bpack(a.z, a.w);
            o.z = bpack(c.x, c.y); o.w = bpack(c.z, c.w);
            xh[i] = o;
        }
    } else {
        // wprep: lane l of entry (kq*8+jt) holds W[jt*16+(l&15)][kq*32+(l>>4)*8..+7]
        const int t = idx * 256 + threadIdx.x;
        if (t >= 2048) return;
        const int l = t & 63;
        const int pair = t >> 6;
        const int kq = pair >> 3;
        const int jt = pair & 7;
        const int s = l & 15;
        const int g = l >> 4;
        const float* src = Wm + ((long long)(jt * 16 + s) << 7) + kq * 32 + g * 8;
        const float4 w0 = *(const float4*)(src);
        const float4 w1 = *(const float4*)(src + 4);
        uint4 o;
        o.x = bpack(w0.x, w0.y); o.y = bpack(w0.z, w0.w);
        o.z = bpack(w1.x, w1.y); o.w = bpack(w1.z, w1.w);
        wfrag[pair * 64 + l] = o;
    }
}

// FUSED scan+zscale: [0,NB): local exclusive scan of row-degrees -> rp, bsum.
//                    [NB,+): z0 = dinv * xh in place; writes dinv[] (f32).
__global__ __launch_bounds__(SCAN_B) void k_scanz(
        const uint32* __restrict__ cnt, int* __restrict__ rp, int* __restrict__ bsum,
        float* __restrict__ dinv, uint4* __restrict__ xh, long long totz,
        int n, int NB) {
    __shared__ int sh[SCAN_B];
    const int b = blockIdx.x;
    const int tid = threadIdx.x;
    if (b < NB) {
        const int i = b * SCAN_B + tid;
        int v = (i < n) ? (int)(cnt[i] >> 16) : 0;
        sh[tid] = v;
        __syncthreads();
        for (int off = 1; off < SCAN_B; off <<= 1) {
            int t = (tid >= off) ? sh[tid - off] : 0;
            __syncthreads();
            sh[tid] += t;
            __syncthreads();
        }
        if (i < n) rp[i] = sh[tid] - v;          // LOCAL exclusive (base added by consumers)
        if (tid == SCAN_B - 1) bsum[b] = sh[SCAN_B - 1];
    } else {
        const long long idx = (long long)(b - NB) * SCAN_B + tid;
        if (idx < totz) {
            const int i = (int)(idx >> 4);
            const float dv = rsqrtf((float)((cnt[i] & 0xffffu) + 1u));
            uint4 v = xh[idx];
            v.x = bpack(dv * blo(v.x), dv * bhi(v.x));
            v.y = bpack(dv * blo(v.y), dv * bhi(v.y));
            v.z = bpack(dv * blo(v.z), dv * bhi(v.z));
            v.w = bpack(dv * blo(v.w), dv * bhi(v.w));
            xh[idx] = v;
            if ((idx & 15) == 0) dinv[i] = dv;
        }
    }
}

// exclusive scan of bsum in place (single block)
__global__ __launch_bounds__(SCAN_B) void k_scan2(int* __restrict__ bsum, int nb) {
    __shared__ int sh[SCAN_B];
    const int tid = threadIdx.x;
    int v = (tid < nb) ? bsum[tid] : 0;
    sh[tid] = v;
    __syncthreads();
    for (int off = 1; off < SCAN_B; off <<= 1) {
        int t = (tid >= off) ? sh[tid - off] : 0;
        __syncthreads();
        sh[tid] += t;
        __syncthreads();
    }
    if (tid < nb) bsum[tid] = sh[tid] - v;
}

// ATOMIC-FREE CSR fill: slot = rp[r] + bsum[r>>10] + rank16[e]; col only (4 B)
__global__ void k_fill(const int2* __restrict__ rows2, const int2* __restrict__ cols2,
                       const ushort* __restrict__ rank16, const int* __restrict__ rp,
                       const int* __restrict__ bsum, int* __restrict__ e4,
                       int E2, int odd,
                       const int* __restrict__ rows, const int* __restrict__ cols) {
    int t = blockIdx.x * blockDim.x + threadIdx.x;
    if (t < E2) {
        const int2 r2 = rows2[t];
        const int2 c2 = cols2[t];
        const ushort2 rk = *(const ushort2*)(rank16 + 2 * t);
        e4[rp[r2.x] + bsum[r2.x >> 10] + rk.x] = c2.x;
        e4[rp[r2.y] + bsum[r2.y >> 10] + rk.y] = c2.y;
    } else if (t == E2 && odd) {
        const int r = rows[2 * E2];
        e4[rp[r] + bsum[r >> 10] + rank16[2 * E2]] = cols[2 * E2];
    }
}

// z-space hop: u[r] = z[r] + sum_{c in N(r)} z[c];  out[r] = dinv[r]^PW * u[r]
// ONE ROW PER 64-LANE WAVE, 4 B (bf16x2)/lane. Unweighted gathers, unroll 8.
// CSR bounds assembled inline from local rp + bsum (+E for the last row).
template <int PW>
__global__ __launch_bounds__(256) void k_spmm(const uint32* __restrict__ xh,
                                              const int* __restrict__ rp,
                                              const int* __restrict__ bsum,
                                              const int* __restrict__ e4,
                                              const float* __restrict__ dinv,
                                              uint32* __restrict__ outh, int n, int Etot) {
    const int row = blockIdx.x * 4 + (threadIdx.x >> 6);
    if (row >= n) return;
    const int l = threadIdx.x & 63;

    const float dv = dinv[row];
    const float sc = (PW == 2) ? dv * dv : dv;

    const uint32 sv = xh[(long long)row * 64 + l];
    float alo = blo(sv);
    float ahi = bhi(sv);

    int e = rp[row] + bsum[row >> 10];
    const int end = (row + 1 < n) ? (rp[row + 1] + bsum[(row + 1) >> 10]) : Etot;
    while (e < end) {
        const int last = end - 1;
        int c[8];
#pragma unroll
        for (int k = 0; k < 8; ++k) {
            const int i = (e + k < last) ? e + k : last;
            c[k] = e4[i];
        }
        uint32 v[8];
#pragma unroll
        for (int k = 0; k < 8; ++k) v[k] = xh[(long long)c[k] * 64 + l];
#pragma unroll
        for (int k = 0; k < 8; ++k) {
            const float w = (e + k <= end - 1) ? 1.0f : 0.0f;
            alo += w * blo(v[k]);
            ahi += w * bhi(v[k]);
        }
        e += 8;
    }

    outh[(long long)row * 64 + l] = bpack(sc * alo, sc * ahi);
}

// C[r][:] = bf16(A[r][:]) @ bf16(W)^T + b via mfma_f32_16x16x32_bf16.
// Block = 4 waves; wave = 64 rows x 64 cols (acc 64 VGPR) -> 4 blocks/CU.
// Tail waves clamp to [n-64, n): duplicate identical stores, no OOB reads.
__global__ __launch_bounds__(256, 4) void k_gemm(const short8* __restrict__ A8,
                                                 const short8* __restrict__ wfrag,
                                                 const float* __restrict__ bias,
                                                 float* __restrict__ xout, int n) {
    const int wid = threadIdx.x >> 6;
    const int rg = wid >> 1;           // row group (0/1): 64 rows each
    const int cg = wid & 1;            // col group (0/1): 64 cols each
    const int l = threadIdx.x & 63;
    const int ls = l & 15;
    const int lg = l >> 4;
    long long row0 = (long long)blockIdx.x * 128 + rg * 64;
    if (row0 + 64 > n) row0 = (long long)n - 64;

    float breg[4];
#pragma unroll
    for (int jt = 0; jt < 4; ++jt) breg[jt] = bias[cg * 64 + jt * 16 + ls];

    f32x4 acc[4][4] = {};

#pragma unroll
    for (int kq = 0; kq < 4; ++kq) {
        short8 af[4];
#pragma unroll
        for (int m = 0; m < 4; ++m)
            af[m] = A8[(row0 + m * 16 + ls) * 16 + kq * 4 + lg];
#pragma unroll
        for (int jt = 0; jt < 4; ++jt) {
            const short8 bf = wfrag[(kq * 8 + cg * 4 + jt) * 64 + l];
#pragma unroll
            for (int m = 0; m < 4; ++m)
                acc[m][jt] = __builtin_amdgcn_mfma_f32_16x16x32_bf16(
                    af[m], bf, acc[m][jt], 0, 0, 0);
        }
    }

#pragma unroll
    for (int m = 0; m < 4; ++m) {
#pragma unroll
        for (int q = 0; q < 4; ++q) {
            const long long row = row0 + m * 16 + lg * 4 + q;
            float* orow = xout + (row << 7) + cg * 64;
#pragma unroll
            for (int jt = 0; jt < 4; ++jt)
                orow[jt * 16 + ls] = acc[m][jt][q] + breg[jt];
        }
    }
}

extern "C" void kernel_launch(void* const* d_in, const int* in_sizes, int n_in,
                              void* d_out, int out_size, void* d_ws, size_t ws_size,
                              hipStream_t stream) {
    const float* x = (const float*)d_in[0];
    const int* ei = (const int*)d_in[1];
    const float* Wm = (const float*)d_in[2];
    const float* bias = (const float*)d_in[3];
    float* out = (float*)d_out;

    const int n = in_sizes[0] / D;
    const int E = in_sizes[1] / 2;
    const int E2 = E >> 1;
    const int odd = E & 1;
    const int NB = (n + SCAN_B - 1) / SCAN_B;

    char* ws = (char*)d_ws;
    size_t off = 0;
    auto alloc = [&](long long bytes) {
        void* p = ws + off;
        off += (size_t)((bytes + 511) & ~511LL);
        return p;
    };
    uint32* cnt   = (uint32*)alloc((long long)n * 4);   // packed degree histogram
    int* rp       = (int*)alloc((long long)n * 4);      // LOCAL exclusive row offsets
    int* bsum     = (int*)alloc((long long)SCAN_B * 4); // scanned block bases
    ushort* rank16= (ushort*)alloc((long long)E * 2);   // per-edge row rank
    int* e4       = (int*)alloc((long long)E * 4);      // CSR col only
    float* dinv   = (float*)alloc((long long)n * 4);
    uint4* xh     = (uint4*)alloc((long long)n * 256);  // bf16 x -> z0 -> hop2 out
    uint4* x1h    = (uint4*)alloc((long long)n * 256);  // bf16 z1
    uint4* wfrag  = (uint4*)alloc(2048LL * 16);         // 32 KB B-fragments

    const int* rows = ei;
    const int* cols = ei + E;
    const int2* rows2 = (const int2*)rows;
    const int2* cols2 = (const int2*)cols;

    const int B = 256;
    const long long totcvt = (long long)n * 16;         // uint4s
    const int ncount = ceil_div_ll(E2 + 1, B);
    const int ncvt = ceil_div_ll(totcvt, B);
    const int cvtLeft = (ncvt > 5 * ncount) ? (ncvt - 5 * ncount) : 0;
    const int grid_fused = 6 * ncount + cvtLeft + 8;
    const int nzs = ceil_div_ll(totcvt, SCAN_B);

    k_init<<<ceil_div_ll(n, B), B, 0, stream>>>(cnt, n);
    // count (atomic-bound, emits ranks) || cvt || wprep — interleaved
    k_fused<<<grid_fused, B, 0, stream>>>(
        rows2, cols2, cnt, rank16, E2, odd, rows, cols,
        (const float4*)x, xh, totcvt, Wm, wfrag, ncount, ncvt, cvtLeft);

    // local scan || z0 = dinv*x (in place) + dinv write
    k_scanz<<<NB + nzs, SCAN_B, 0, stream>>>(cnt, rp, bsum, dinv, xh, totcvt, n, NB);
    k_scan2<<<1, SCAN_B, 0, stream>>>(bsum, NB);
    // atomic-free CSR fill (col-only, base assembled inline)
    k_fill<<<ceil_div_ll(E2 + 1, B), B, 0, stream>>>(
        rows2, cols2, rank16, rp, bsum, e4, E2, odd, rows, cols);

    // hop 1 (z1 = dinv^2*(z0 + sum z0)), hop 2 (x2 = dinv*(z1 + sum z1))
    k_spmm<2><<<ceil_div_ll(n, 4), B, 0, stream>>>(
        (const uint32*)xh, rp, bsum, e4, dinv, (uint32*)x1h, n, E);
    k_spmm<1><<<ceil_div_ll(n, 4), B, 0, stream>>>(
        (const uint32*)x1h, rp, bsum, e4, dinv, (uint32*)xh, n, E);

    k_gemm<<<ceil_div_ll(n, 128), B, 0, stream>>>(
        (const short8*)xh, (const short8*)wfrag, bias, out, n);
}